// Round 1
// baseline (331.063 us; speedup 1.0000x reference)
//
#include <hip/hip_runtime.h>
#include <hip/hip_bf16.h>
#include <stdint.h>

typedef __bf16 bf16_t;
typedef __bf16 bf16x8 __attribute__((ext_vector_type(8)));
typedef __bf16 bf16x4 __attribute__((ext_vector_type(4)));
typedef float floatx4 __attribute__((ext_vector_type(4)));

#define QSCALE 0.180336879f  /* 0.125 * log2(e) : fold score scale + exp2 domain into Q */

// ---------------------------------------------------------------- fp32 -> bf16
__global__ __launch_bounds__(256) void cvt_f32_bf16(const float* __restrict__ in,
                                                    bf16_t* __restrict__ out, int n4) {
    int i = blockIdx.x * 256 + threadIdx.x;
    if (i < n4) {
        float4 v = ((const float4*)in)[i];
        bf16x4 o;
        o[0] = (bf16_t)v.x; o[1] = (bf16_t)v.y; o[2] = (bf16_t)v.z; o[3] = (bf16_t)v.w;
        ((bf16x4*)out)[i] = o;
    }
}

// ---------------------------------------------------------------- QKV GEMM
// A: inp_bf (4096 x 1024), Bw: Wqkv_bf (3072 x 1024, N x K), bias fp32 (3072)
// out: qk (4096 x 2048)  [q cols 0..1023 scaled by QSCALE, k cols 1024..2047]
//      vT (2048 x 2048)  [row = (b*16+h)*64 + d, col = t]
__global__ __launch_bounds__(256, 2)
void gemm_qkv(const bf16_t* __restrict__ A, const bf16_t* __restrict__ Bw,
              const float* __restrict__ bias,
              bf16_t* __restrict__ qk, bf16_t* __restrict__ vT) {
    constexpr int K = 1024;
    __shared__ bf16_t lA[128 * 32];
    __shared__ bf16_t lB[128 * 32];
    const int tid  = threadIdx.x;
    const int lane = tid & 63, wave = tid >> 6;
    const int quad = lane >> 4, l16 = lane & 15;
    const int wy = wave >> 1, wx = wave & 1;
    const int bm = blockIdx.y * 128, bn = blockIdx.x * 128;

    const int c0 = tid, c1 = tid + 256;          // 16B chunks (row = c>>2, col8 = (c&3)*8)
    const int r0 = c0 >> 2, cc0 = (c0 & 3) * 8;
    const int r1 = c1 >> 2, cc1 = (c1 & 3) * 8;
    const bf16_t* Ap0 = A + (size_t)(bm + r0) * K + cc0;
    const bf16_t* Ap1 = A + (size_t)(bm + r1) * K + cc1;
    const bf16_t* Bp0 = Bw + (size_t)(bn + r0) * K + cc0;
    const bf16_t* Bp1 = Bw + (size_t)(bn + r1) * K + cc1;

    floatx4 acc[4][4] = {};

    for (int kt = 0; kt < K; kt += 32) {
        bf16x8 a0 = *(const bf16x8*)(Ap0 + kt);
        bf16x8 a1 = *(const bf16x8*)(Ap1 + kt);
        bf16x8 b0 = *(const bf16x8*)(Bp0 + kt);
        bf16x8 b1 = *(const bf16x8*)(Bp1 + kt);
        __syncthreads();
        *(bf16x8*)(lA + c0 * 8) = a0;
        *(bf16x8*)(lA + c1 * 8) = a1;
        *(bf16x8*)(lB + c0 * 8) = b0;
        *(bf16x8*)(lB + c1 * 8) = b1;
        __syncthreads();
        bf16x8 af[4], bfr[4];
#pragma unroll
        for (int i = 0; i < 4; i++) {
            af[i]  = *(const bf16x8*)(lA + (wy * 64 + i * 16 + l16) * 32 + quad * 8);
            bfr[i] = *(const bf16x8*)(lB + (wx * 64 + i * 16 + l16) * 32 + quad * 8);
        }
#pragma unroll
        for (int i = 0; i < 4; i++)
#pragma unroll
            for (int j = 0; j < 4; j++)
                acc[i][j] = __builtin_amdgcn_mfma_f32_16x16x32_bf16(af[i], bfr[j], acc[i][j], 0, 0, 0);
    }

    const bool is_v = (bn >= 2048);   // uniform per block (tiles don't straddle 2048)
#pragma unroll
    for (int j = 0; j < 4; j++) {
        const int n = bn + wx * 64 + j * 16 + l16;
        const float bv = bias[n];
        const bool isq = (n < 1024);
#pragma unroll
        for (int i = 0; i < 4; i++) {
            const int mbase = bm + wy * 64 + i * 16 + quad * 4;
            if (!is_v) {
#pragma unroll
                for (int r = 0; r < 4; r++) {
                    float c = acc[i][j][r] + bv;
                    if (isq) c *= QSCALE;
                    qk[(size_t)(mbase + r) * 2048 + n] = (bf16_t)c;
                }
            } else {
                const int nn = n - 2048;             // h*64 + d
                const int b  = mbase >> 11;
                const int t  = mbase & 2047;         // multiple of 4
                const int vrow = b * 1024 + nn;      // (b*16+h)*64 + d
                bf16x4 pack;
#pragma unroll
                for (int r = 0; r < 4; r++) pack[r] = (bf16_t)(acc[i][j][r] + bv);
                *(bf16x4*)(vT + (size_t)vrow * 2048 + t) = pack;
            }
        }
    }
}

// ---------------------------------------------------------------- flash attention
// qk: (4096 x 2048) bf16 [q scaled], vT: (2048 x 2048), av out: (4096 x 1024) permuted
__global__ __launch_bounds__(256, 2)
void attn_kernel(const bf16_t* __restrict__ qk, const bf16_t* __restrict__ vT,
                 bf16_t* __restrict__ av) {
    __shared__ bf16_t P_lds[4][32 * 128];
    const int tid  = threadIdx.x;
    const int lane = tid & 63, wave = tid >> 6;
    const int quad = lane >> 4, l16 = lane & 15;
    const int bid = blockIdx.x;
    const int qt = bid & 15;        // query tile (128 rows)
    const int hl = bid >> 4;        // b*16 + h in [0,32)
    const int b = hl >> 4, h = hl & 15;

    const bf16_t* Qbase = qk + (size_t)(b * 2048 + qt * 128 + wave * 32) * 2048 + h * 64;
    const bf16_t* Kbase = qk + (size_t)(b * 2048) * 2048 + 1024 + h * 64;
    const bf16_t* Vbase = vT + (size_t)(hl * 64) * 2048;
    bf16_t* Pw = &P_lds[wave][0];

    bf16x8 qf[2][2];
#pragma unroll
    for (int rt = 0; rt < 2; rt++)
#pragma unroll
        for (int kc = 0; kc < 2; kc++)
            qf[rt][kc] = *(const bf16x8*)(Qbase + (size_t)(rt * 16 + l16) * 2048 + kc * 32 + quad * 8);

    float mrow[2][4], lrow[2][4];
    floatx4 accO[2][4] = {};
#pragma unroll
    for (int rt = 0; rt < 2; rt++)
#pragma unroll
        for (int r = 0; r < 4; r++) { mrow[rt][r] = -1e30f; lrow[rt][r] = 0.f; }

    for (int kt = 0; kt < 2048; kt += 128) {
        floatx4 s[2][8] = {};
#pragma unroll
        for (int nt = 0; nt < 8; nt++) {
            const bf16_t* kp = Kbase + (size_t)(kt + nt * 16 + l16) * 2048 + quad * 8;
            bf16x8 k0 = *(const bf16x8*)(kp);
            bf16x8 k1 = *(const bf16x8*)(kp + 32);
#pragma unroll
            for (int rt = 0; rt < 2; rt++) {
                s[rt][nt] = __builtin_amdgcn_mfma_f32_16x16x32_bf16(qf[rt][0], k0, s[rt][nt], 0, 0, 0);
                s[rt][nt] = __builtin_amdgcn_mfma_f32_16x16x32_bf16(qf[rt][1], k1, s[rt][nt], 0, 0, 0);
            }
        }
#pragma unroll
        for (int rt = 0; rt < 2; rt++) {
            float alpha[4], lsum[4];
#pragma unroll
            for (int r = 0; r < 4; r++) {
                float mx = s[rt][0][r];
#pragma unroll
                for (int nt = 1; nt < 8; nt++) mx = fmaxf(mx, s[rt][nt][r]);
                mx = fmaxf(mx, __shfl_xor(mx, 1));
                mx = fmaxf(mx, __shfl_xor(mx, 2));
                mx = fmaxf(mx, __shfl_xor(mx, 4));
                mx = fmaxf(mx, __shfl_xor(mx, 8));
                float mnew = fmaxf(mrow[rt][r], mx);
                alpha[r] = exp2f(mrow[rt][r] - mnew);
                mrow[rt][r] = mnew;
                lsum[r] = 0.f;
            }
#pragma unroll
            for (int nt = 0; nt < 8; nt++)
#pragma unroll
                for (int r = 0; r < 4; r++) {
                    float p = exp2f(s[rt][nt][r] - mrow[rt][r]);
                    lsum[r] += p;
                    Pw[(rt * 16 + quad * 4 + r) * 128 + nt * 16 + l16] = (bf16_t)p;
                }
#pragma unroll
            for (int r = 0; r < 4; r++) {
                float ls = lsum[r];
                ls += __shfl_xor(ls, 1);
                ls += __shfl_xor(ls, 2);
                ls += __shfl_xor(ls, 4);
                ls += __shfl_xor(ls, 8);
                lrow[rt][r] = lrow[rt][r] * alpha[r] + ls;
            }
#pragma unroll
            for (int ct = 0; ct < 4; ct++)
#pragma unroll
                for (int r = 0; r < 4; r++) accO[rt][ct][r] *= alpha[r];
        }
        // PV: P (A-layout via LDS), V^T fragments from global
#pragma unroll
        for (int kc = 0; kc < 4; kc++) {
            bf16x8 pf[2];
#pragma unroll
            for (int rt = 0; rt < 2; rt++)
                pf[rt] = *(const bf16x8*)(&Pw[(rt * 16 + l16) * 128 + kc * 32 + quad * 8]);
#pragma unroll
            for (int ct = 0; ct < 4; ct++) {
                bf16x8 vf = *(const bf16x8*)(Vbase + (size_t)(ct * 16 + l16) * 2048 + kt + kc * 32 + quad * 8);
#pragma unroll
                for (int rt = 0; rt < 2; rt++)
                    accO[rt][ct] = __builtin_amdgcn_mfma_f32_16x16x32_bf16(pf[rt], vf, accO[rt][ct], 0, 0, 0);
            }
        }
    }
    // epilogue with "faithful bug" permutation: dest row (hl&1)*2048+t, col (hl>>1)*64+d
    const int b2 = hl & 1;
    const int colb = (hl >> 1) * 64;
    bf16_t* outb = av + (size_t)(b2 * 2048 + qt * 128 + wave * 32) * 1024 + colb;
#pragma unroll
    for (int rt = 0; rt < 2; rt++)
#pragma unroll
        for (int r = 0; r < 4; r++) {
            const float inv = 1.0f / lrow[rt][r];
            const int row = rt * 16 + quad * 4 + r;
#pragma unroll
            for (int ct = 0; ct < 4; ct++)
                outb[(size_t)row * 1024 + ct * 16 + l16] = (bf16_t)(accO[rt][ct][r] * inv);
        }
}

// ---------------------------------------------------------------- O GEMM (no bias, fp32 out)
// A: av (4096 x 1024), Bw: Wo_bf (1024 x 1024, N x K), out: attn_out fp32 (4096 x 1024)
__global__ __launch_bounds__(256, 2)
void gemm_o(const bf16_t* __restrict__ A, const bf16_t* __restrict__ Bw,
            float* __restrict__ out) {
    constexpr int K = 1024;
    __shared__ bf16_t lA[128 * 32];
    __shared__ bf16_t lB[128 * 32];
    const int tid  = threadIdx.x;
    const int lane = tid & 63, wave = tid >> 6;
    const int quad = lane >> 4, l16 = lane & 15;
    const int wy = wave >> 1, wx = wave & 1;
    const int bm = blockIdx.y * 128, bn = blockIdx.x * 128;

    const int c0 = tid, c1 = tid + 256;
    const int r0 = c0 >> 2, cc0 = (c0 & 3) * 8;
    const int r1 = c1 >> 2, cc1 = (c1 & 3) * 8;
    const bf16_t* Ap0 = A + (size_t)(bm + r0) * K + cc0;
    const bf16_t* Ap1 = A + (size_t)(bm + r1) * K + cc1;
    const bf16_t* Bp0 = Bw + (size_t)(bn + r0) * K + cc0;
    const bf16_t* Bp1 = Bw + (size_t)(bn + r1) * K + cc1;

    floatx4 acc[4][4] = {};
    for (int kt = 0; kt < K; kt += 32) {
        bf16x8 a0 = *(const bf16x8*)(Ap0 + kt);
        bf16x8 a1 = *(const bf16x8*)(Ap1 + kt);
        bf16x8 b0 = *(const bf16x8*)(Bp0 + kt);
        bf16x8 b1 = *(const bf16x8*)(Bp1 + kt);
        __syncthreads();
        *(bf16x8*)(lA + c0 * 8) = a0;
        *(bf16x8*)(lA + c1 * 8) = a1;
        *(bf16x8*)(lB + c0 * 8) = b0;
        *(bf16x8*)(lB + c1 * 8) = b1;
        __syncthreads();
        bf16x8 af[4], bfr[4];
#pragma unroll
        for (int i = 0; i < 4; i++) {
            af[i]  = *(const bf16x8*)(lA + (wy * 64 + i * 16 + l16) * 32 + quad * 8);
            bfr[i] = *(const bf16x8*)(lB + (wx * 64 + i * 16 + l16) * 32 + quad * 8);
        }
#pragma unroll
        for (int i = 0; i < 4; i++)
#pragma unroll
            for (int j = 0; j < 4; j++)
                acc[i][j] = __builtin_amdgcn_mfma_f32_16x16x32_bf16(af[i], bfr[j], acc[i][j], 0, 0, 0);
    }
#pragma unroll
    for (int j = 0; j < 4; j++) {
        const int n = bn + wx * 64 + j * 16 + l16;
#pragma unroll
        for (int i = 0; i < 4; i++) {
            const int mbase = bm + wy * 64 + i * 16 + quad * 4;
#pragma unroll
            for (int r = 0; r < 4; r++)
                out[(size_t)(mbase + r) * 1024 + n] = acc[i][j][r];
        }
    }
}

// ---------------------------------------------------------------- residual + LayerNorm
__global__ __launch_bounds__(256)
void ln_kernel(const float* __restrict__ inp, const float* __restrict__ ao,
               const float* __restrict__ gamma, const float* __restrict__ beta,
               float* __restrict__ out) {
    const int row = blockIdx.x, tid = threadIdx.x;
    const int wave = tid >> 6, lane = tid & 63;
    float4 a = ((const float4*)(inp + (size_t)row * 1024))[tid];
    float4 c = ((const float4*)(ao + (size_t)row * 1024))[tid];
    float x0 = a.x + c.x, x1 = a.y + c.y, x2 = a.z + c.z, x3 = a.w + c.w;
    float s = x0 + x1 + x2 + x3;
    float sq = x0 * x0 + x1 * x1 + x2 * x2 + x3 * x3;
#pragma unroll
    for (int m = 32; m >= 1; m >>= 1) {
        s += __shfl_xor(s, m);
        sq += __shfl_xor(sq, m);
    }
    __shared__ float rs[4], rq[4];
    if (lane == 0) { rs[wave] = s; rq[wave] = sq; }
    __syncthreads();
    s = rs[0] + rs[1] + rs[2] + rs[3];
    sq = rq[0] + rq[1] + rq[2] + rq[3];
    const float mu = s * (1.0f / 1024.0f);
    const float var = sq * (1.0f / 1024.0f) - mu * mu;
    const float rstd = rsqrtf(var + 1e-5f);
    float4 g = ((const float4*)gamma)[tid], bt = ((const float4*)beta)[tid];
    float4 o;
    o.x = (x0 - mu) * rstd * g.x + bt.x;
    o.y = (x1 - mu) * rstd * g.y + bt.y;
    o.z = (x2 - mu) * rstd * g.z + bt.z;
    o.w = (x3 - mu) * rstd * g.w + bt.w;
    ((float4*)(out + (size_t)row * 1024))[tid] = o;
}

// ---------------------------------------------------------------- launch
extern "C" void kernel_launch(void* const* d_in, const int* in_sizes, int n_in,
                              void* d_out, int out_size, void* d_ws, size_t ws_size,
                              hipStream_t stream) {
    const float* inp   = (const float*)d_in[0];  // (2,2048,1024)
    const float* Wqkv  = (const float*)d_in[1];  // (3072,1024)
    const float* bqkv  = (const float*)d_in[2];  // (3072,)
    const float* Wo    = (const float*)d_in[3];  // (1024,1024)
    const float* gamma = (const float*)d_in[4];
    const float* beta  = (const float*)d_in[5];
    float* out = (float*)d_out;

    char* ws = (char*)d_ws;
    bf16_t* inp_bf  = (bf16_t*)(ws);                       //  8 MB
    bf16_t* wqkv_bf = (bf16_t*)(ws + (8u << 20));          //  6 MB
    bf16_t* wo_bf   = (bf16_t*)(ws + (14u << 20));         //  2 MB
    bf16_t* qk_buf  = (bf16_t*)(ws + (16u << 20));         // 16 MB
    bf16_t* vT_buf  = (bf16_t*)(ws + (32u << 20));         //  8 MB
    bf16_t* av_buf  = (bf16_t*)(ws + (40u << 20));         //  8 MB
    float*  ao_buf  = (float*)(ws + (48u << 20));          // 16 MB

    cvt_f32_bf16<<<4096, 256, 0, stream>>>(inp, inp_bf, 4096 * 1024 / 4);
    cvt_f32_bf16<<<3072, 256, 0, stream>>>(Wqkv, wqkv_bf, 3072 * 1024 / 4);
    cvt_f32_bf16<<<1024, 256, 0, stream>>>(Wo, wo_bf, 1024 * 1024 / 4);

    gemm_qkv<<<dim3(24, 32), 256, 0, stream>>>(inp_bf, wqkv_bf, bqkv, qk_buf, vT_buf);
    attn_kernel<<<512, 256, 0, stream>>>(qk_buf, vT_buf, av_buf);
    gemm_o<<<dim3(8, 32), 256, 0, stream>>>(av_buf, wo_bf, ao_buf);
    ln_kernel<<<4096, 256, 0, stream>>>(inp, ao_buf, gamma, beta, out);
}